// Round 4
// baseline (983.671 us; speedup 1.0000x reference)
//
#include <hip/hip_runtime.h>
#include <hip/hip_bf16.h>

using bf16 = __hip_bfloat16;
typedef __bf16 bf16x8 __attribute__((ext_vector_type(8)));
typedef float f32x4 __attribute__((ext_vector_type(4)));

#define MFMA16(A, B, C) __builtin_amdgcn_mfma_f32_16x16x32_bf16((A), (B), (C), 0, 0, 0)

__device__ __forceinline__ void store_elem(bf16* p, float v) { *p = __float2bfloat16(v); }
__device__ __forceinline__ void store_elem(float* p, float v) { *p = v; }

// ---------------------------------------------------------------------------
// fp32 -> bf16 convert, 4 elems/thread. n must be multiple of 1024.
// ---------------------------------------------------------------------------
__global__ void cvt_fp32_bf16(const float* __restrict__ src, bf16* __restrict__ dst) {
    int i = (blockIdx.x * 256 + threadIdx.x) * 4;
    float4 v = *(const float4*)(src + i);
    bf16 o[4] = {__float2bfloat16(v.x), __float2bfloat16(v.y),
                 __float2bfloat16(v.z), __float2bfloat16(v.w)};
    *(uint2*)(dst + i) = *(const uint2*)o;
}

// ---------------------------------------------------------------------------
// Weight transpose + convert: src K x N fp32 (row-major) -> dst N x K bf16.
// grid (N/32, K/32), block (32,8). All dims are multiples of 32.
// ---------------------------------------------------------------------------
__global__ void wtrans(const float* __restrict__ src, bf16* __restrict__ dst,
                       int K, int N) {
    __shared__ bf16 t[32][33];
    int n0 = blockIdx.x * 32, k0 = blockIdx.y * 32;
    #pragma unroll
    for (int i = 0; i < 4; ++i) {
        int r = threadIdx.y + i * 8;  // k-local
        t[r][threadIdx.x] = __float2bfloat16(src[(size_t)(k0 + r) * N + n0 + threadIdx.x]);
    }
    __syncthreads();
    #pragma unroll
    for (int i = 0; i < 4; ++i) {
        int r = threadIdx.y + i * 8;  // n-local
        dst[(size_t)(n0 + r) * K + k0 + threadIdx.x] = t[threadIdx.x][r];
    }
}

// zero-fill 64*2048 bf16 (pad rows of WcatT). grid 512, block 256.
__global__ void zerofill(bf16* __restrict__ p) {
    p[blockIdx.x * 256 + threadIdx.x] = __float2bfloat16(0.0f);
}

// ---------------------------------------------------------------------------
// GEMM: C[M][N] = A[M][K] @ Bt[N][K]^T, bf16 in, fp32 acc, CT out (bf16/f32).
// 128x128 tile, BK=32, 256 threads (4 waves), wave -> 64x64, 4x4 MFMA tiles.
// grid (N/128, M/128).
// ---------------------------------------------------------------------------
template <typename CT>
__global__ __launch_bounds__(256) void gemm_bt(
    const bf16* __restrict__ A, int lda,
    const bf16* __restrict__ Bt, int ldb,
    CT* __restrict__ C, int ldc, int K) {
    __shared__ bf16 As[128 * 32];
    __shared__ bf16 Bs[128 * 32];
    const int m0 = blockIdx.y * 128;
    const int n0 = blockIdx.x * 128;
    const int tid = threadIdx.x;
    const int lane = tid & 63;
    const int wave = tid >> 6;
    const int wm = (wave >> 1) * 64;
    const int wn = (wave & 1) * 64;
    const int lr = lane & 15;
    const int lq = lane >> 4;
    const int sr = tid >> 2;        // staging row 0..63
    const int sc = (tid & 3) * 8;   // staging col 0,8,16,24

    f32x4 acc[4][4] = {};

    for (int k0 = 0; k0 < K; k0 += 32) {
        uint4 a0 = *(const uint4*)(A + (size_t)(m0 + sr) * lda + k0 + sc);
        uint4 a1 = *(const uint4*)(A + (size_t)(m0 + sr + 64) * lda + k0 + sc);
        uint4 b0 = *(const uint4*)(Bt + (size_t)(n0 + sr) * ldb + k0 + sc);
        uint4 b1 = *(const uint4*)(Bt + (size_t)(n0 + sr + 64) * ldb + k0 + sc);
        __syncthreads();
        *(uint4*)(As + sr * 32 + sc) = a0;
        *(uint4*)(As + (sr + 64) * 32 + sc) = a1;
        *(uint4*)(Bs + sr * 32 + sc) = b0;
        *(uint4*)(Bs + (sr + 64) * 32 + sc) = b1;
        __syncthreads();
        bf16x8 af[4], bfr[4];
        #pragma unroll
        for (int t = 0; t < 4; ++t) {
            af[t]  = *(const bf16x8*)(As + (wm + t * 16 + lr) * 32 + lq * 8);
            bfr[t] = *(const bf16x8*)(Bs + (wn + t * 16 + lr) * 32 + lq * 8);
        }
        #pragma unroll
        for (int mt = 0; mt < 4; ++mt)
            #pragma unroll
            for (int nt = 0; nt < 4; ++nt)
                acc[mt][nt] = MFMA16(af[mt], bfr[nt], acc[mt][nt]);
    }
    #pragma unroll
    for (int mt = 0; mt < 4; ++mt)
        #pragma unroll
        for (int nt = 0; nt < 4; ++nt)
            #pragma unroll
            for (int r = 0; r < 4; ++r) {
                int row = m0 + wm + mt * 16 + lq * 4 + r;
                int col = n0 + wn + nt * 16 + lr;
                store_elem(C + (size_t)row * ldc + col, acc[mt][nt][r]);
            }
}

// ---------------------------------------------------------------------------
// kv GEMM with split epilogue: C col j (j in 0..4095) of kv = c_kv @ Wukv.
// h = j>>8, r = j&255. r<128 -> k_nope into kbuf[row][h*128+r];
// r>=128 -> v scattered TRANSPOSED into vT[(b*16+h)*128 + (r-128)][s].
// grid (32, 32), K=512.
// ---------------------------------------------------------------------------
__global__ __launch_bounds__(256) void gemm_kv(
    const bf16* __restrict__ A, int lda,
    const bf16* __restrict__ Bt, int ldb,
    bf16* __restrict__ kbuf, bf16* __restrict__ vT, int K) {
    __shared__ bf16 As[128 * 32];
    __shared__ bf16 Bs[128 * 32];
    const int m0 = blockIdx.y * 128;
    const int n0 = blockIdx.x * 128;
    const int tid = threadIdx.x;
    const int lane = tid & 63;
    const int wave = tid >> 6;
    const int wm = (wave >> 1) * 64;
    const int wn = (wave & 1) * 64;
    const int lr = lane & 15;
    const int lq = lane >> 4;
    const int sr = tid >> 2;
    const int sc = (tid & 3) * 8;

    f32x4 acc[4][4] = {};

    for (int k0 = 0; k0 < K; k0 += 32) {
        uint4 a0 = *(const uint4*)(A + (size_t)(m0 + sr) * lda + k0 + sc);
        uint4 a1 = *(const uint4*)(A + (size_t)(m0 + sr + 64) * lda + k0 + sc);
        uint4 b0 = *(const uint4*)(Bt + (size_t)(n0 + sr) * ldb + k0 + sc);
        uint4 b1 = *(const uint4*)(Bt + (size_t)(n0 + sr + 64) * ldb + k0 + sc);
        __syncthreads();
        *(uint4*)(As + sr * 32 + sc) = a0;
        *(uint4*)(As + (sr + 64) * 32 + sc) = a1;
        *(uint4*)(Bs + sr * 32 + sc) = b0;
        *(uint4*)(Bs + (sr + 64) * 32 + sc) = b1;
        __syncthreads();
        bf16x8 af[4], bfr[4];
        #pragma unroll
        for (int t = 0; t < 4; ++t) {
            af[t]  = *(const bf16x8*)(As + (wm + t * 16 + lr) * 32 + lq * 8);
            bfr[t] = *(const bf16x8*)(Bs + (wn + t * 16 + lr) * 32 + lq * 8);
        }
        #pragma unroll
        for (int mt = 0; mt < 4; ++mt)
            #pragma unroll
            for (int nt = 0; nt < 4; ++nt)
                acc[mt][nt] = MFMA16(af[mt], bfr[nt], acc[mt][nt]);
    }
    #pragma unroll
    for (int mt = 0; mt < 4; ++mt)
        #pragma unroll
        for (int nt = 0; nt < 4; ++nt) {
            int colbase = n0 + wn + nt * 16;   // 16-aligned, never crosses 256
            int h = colbase >> 8;
            int rr = (colbase & 255) + lr;     // 0..255
            #pragma unroll
            for (int r = 0; r < 4; ++r) {
                int row = m0 + wm + mt * 16 + lq * 4 + r;  // 0..4095
                bf16 val = __float2bfloat16(acc[mt][nt][r]);
                if (rr < 128) {
                    kbuf[(size_t)row * 2048 + h * 128 + rr] = val;
                } else {
                    int dv = rr - 128;
                    int b = row >> 11, s = row & 2047;
                    vT[((size_t)((b * 16 + h) * 128 + dv)) * 2048 + s] = val;
                }
            }
        }
}

// ---------------------------------------------------------------------------
// RoPE in-place on XW[4096][3712]: 16 q-rope vectors (cols h*192+128..+63)
// and k_rope (cols 3072..3135). grid (17, 1024), block (64,4).
// ---------------------------------------------------------------------------
__global__ void rope_kernel(bf16* __restrict__ XW) {
    int v = blockIdx.x;                       // 0..16
    int row = blockIdx.y * 4 + threadIdx.y;   // 0..4095
    int i = threadIdx.x;                      // 0..63
    int s = row & 2047;
    int cbase = (v < 16) ? v * 192 + 128 : 3072;
    size_t base = (size_t)row * 3712 + cbase;
    float xi = __bfloat162float(XW[base + i]);
    float xp = __shfl_xor(xi, 32);            // partner element x[i^32]
    int j = i & 31;
    float inv = exp2f(-(float)j * (13.287712379549449f / 32.0f));  // 10000^(-j/32)
    float ang = (float)s * inv;
    float c = cosf(ang), sn = sinf(ang);
    float res = (i < 32) ? (xi * c - xp * sn) : (xi * c + xp * sn);
    XW[base + i] = __float2bfloat16(res);
}

// ---------------------------------------------------------------------------
// Flash attention (causal). grid (32 qtiles, 32 bh), block 256 (4 waves).
// Wave handles 16 q rows; iterates 32-key tiles with online softmax.
// XW[4096][3712]: q at h*192 (128 nope + 64 rope), k_rope at 3072.
// kbuf[2][2048][2048]: per head h: k_nope at cols h*128..h*128+127.
// vT[32][128][2048]. attn_out[4096][2048].
// ---------------------------------------------------------------------------
__global__ __launch_bounds__(256) void attn_kernel(
    const bf16* __restrict__ XW, const bf16* __restrict__ kbuf,
    const bf16* __restrict__ vT, bf16* __restrict__ attn_out) {
    const int bh = blockIdx.y, b = bh >> 4, h = bh & 15;
    const int wave = threadIdx.x >> 6;
    const int lane = threadIdx.x & 63;
    const int lr = lane & 15, lq = lane >> 4;
    const int q0 = blockIdx.x * 64 + wave * 16;

    __shared__ bf16 lds_p[4][16 * 32];

    const bf16* xwb = XW + (size_t)b * 2048 * 3712;
    const bf16* kb  = kbuf + (size_t)b * 2048 * 2048;
    const bf16* vTb = vT + (size_t)bh * 128 * 2048;

    // Q fragments: 192 features = 6 chunks of 32
    bf16x8 qf[6];
    const size_t qrowoff = (size_t)(q0 + lr) * 3712 + h * 192;
    #pragma unroll
    for (int c = 0; c < 6; ++c)
        qf[c] = *(const bf16x8*)(xwb + qrowoff + c * 32 + lq * 8);

    f32x4 o[8] = {};
    float m_i[4], l_i[4];
    #pragma unroll
    for (int r = 0; r < 4; ++r) { m_i[r] = -1e30f; l_i[r] = 0.0f; }

    const float scale = 0.07216878364870323f;  // 1/sqrt(192)
    const float LOG2E = 1.4426950408889634f;

    for (int n0 = 0; n0 < q0 + 16; n0 += 32) {
        int kr0 = min(n0 + lr, 2047);
        int kr1 = min(n0 + 16 + lr, 2047);
        const bf16* k0p = kb + (size_t)kr0 * 2048 + h * 128;
        const bf16* k1p = kb + (size_t)kr1 * 2048 + h * 128;
        const bf16* x0p = xwb + (size_t)kr0 * 3712 + 3072;
        const bf16* x1p = xwb + (size_t)kr1 * 3712 + 3072;
        f32x4 s0 = {}, s1 = {};
        #pragma unroll
        for (int c = 0; c < 4; ++c) {
            s0 = MFMA16(qf[c], *(const bf16x8*)(k0p + c * 32 + lq * 8), s0);
            s1 = MFMA16(qf[c], *(const bf16x8*)(k1p + c * 32 + lq * 8), s1);
        }
        #pragma unroll
        for (int c = 0; c < 2; ++c) {
            s0 = MFMA16(qf[4 + c], *(const bf16x8*)(x0p + c * 32 + lq * 8), s0);
            s1 = MFMA16(qf[4 + c], *(const bf16x8*)(x1p + c * 32 + lq * 8), s1);
        }
        // online softmax per accumulator row r (q row = q0 + lq*4 + r)
        #pragma unroll
        for (int r = 0; r < 4; ++r) {
            int qrow = q0 + lq * 4 + r;
            float a0 = (n0 + lr <= qrow) ? s0[r] * scale : -1e30f;
            float a1 = (n0 + 16 + lr <= qrow) ? s1[r] * scale : -1e30f;
            float t = fmaxf(a0, a1);
            #pragma unroll
            for (int off = 1; off < 16; off <<= 1) t = fmaxf(t, __shfl_xor(t, off));
            float mnew = fmaxf(m_i[r], t);
            float alpha = exp2f((m_i[r] - mnew) * LOG2E);
            float p0 = exp2f((a0 - mnew) * LOG2E);
            float p1 = exp2f((a1 - mnew) * LOG2E);
            m_i[r] = mnew;
            float ps = p0 + p1;
            #pragma unroll
            for (int off = 1; off < 16; off <<= 1) ps += __shfl_xor(ps, off);
            l_i[r] = l_i[r] * alpha + ps;
            #pragma unroll
            for (int dt = 0; dt < 8; ++dt) o[dt][r] *= alpha;
            lds_p[wave][(lq * 4 + r) * 32 + lr] = __float2bfloat16(p0);
            lds_p[wave][(lq * 4 + r) * 32 + 16 + lr] = __float2bfloat16(p1);
        }
        // in-wave LDS RAW: compiler barrier + explicit wait for the ds_writes
        __asm__ volatile("s_waitcnt lgkmcnt(0)" ::: "memory");
        bf16x8 pf = *(const bf16x8*)(&lds_p[wave][lr * 32 + lq * 8]);
        int vb = n0 + lq * 8;
        #pragma unroll
        for (int dt = 0; dt < 8; ++dt) {
            bf16x8 vf = *(const bf16x8*)(vTb + (size_t)(dt * 16 + lr) * 2048 + vb);
            o[dt] = MFMA16(pf, vf, o[dt]);
        }
    }
    #pragma unroll
    for (int r = 0; r < 4; ++r) {
        float invl = 1.0f / l_i[r];
        int qrow = q0 + lq * 4 + r;
        size_t orow = (size_t)(b * 2048 + qrow) * 2048 + h * 128;
        #pragma unroll
        for (int dt = 0; dt < 8; ++dt)
            attn_out[orow + dt * 16 + lr] = __float2bfloat16(o[dt][r] * invl);
    }
}

// ---------------------------------------------------------------------------
extern "C" void kernel_launch(void* const* d_in, const int* in_sizes, int n_in,
                              void* d_out, int out_size, void* d_ws, size_t ws_size,
                              hipStream_t stream) {
    // Reference setup_inputs() builds float32 tensors -> read as const float*.
    const float* x    = (const float*)d_in[0];
    const float* Wq   = (const float*)d_in[1];
    const float* Wdkv = (const float*)d_in[2];
    const float* Wkr  = (const float*)d_in[3];
    const float* Wukv = (const float*)d_in[4];
    const float* Wo   = (const float*)d_in[5];
    float* out = (float*)d_out;  // reference output dtype is float32

    // Workspace layout (80,740,352 bytes total), time-sliced aliasing:
    //   XW       @ 0          : 4096 x 3712 bf16 = 30,408,704   [gemm -> attn]
    //   kbuf     @ 30,408,704 : 2 x 2048 x 2048  = 16,777,216   [gemm_kv -> attn]
    //   vT       @ 47,185,920 : 32 x 128 x 2048  = 16,777,216   [gemm_kv -> attn]
    //   attn_out @ 63,963,136 : 4096 x 2048      = 16,777,216   [attn -> final gemm]
    //   xb     aliases kbuf slot (16,777,216), dead before gemm_kv writes kbuf
    //   WcatT  aliases vT slot   (15,204,352), dead before gemm_kv writes vT
    //   WukvT  aliases attn_out slot (4,194,304), dead before attn writes attn_out
    //   WoT    aliases vT slot   (8,388,608), written after attn
    char* ws = (char*)d_ws;
    bf16* XW       = (bf16*)(ws);
    bf16* kbuf     = (bf16*)(ws + 30408704);
    bf16* vT       = (bf16*)(ws + 47185920);
    bf16* attn_out = (bf16*)(ws + 63963136);
    bf16* xb       = (bf16*)(ws + 30408704);  // alias kbuf
    bf16* WcatT    = (bf16*)(ws + 47185920);  // alias vT
    bf16* WukvT    = (bf16*)(ws + 63963136);  // alias attn_out
    bf16* WoT      = (bf16*)(ws + 47185920);  // alias vT (after attn)

    dim3 tb(32, 8);
    // Convert x (fp32 -> bf16): 8,388,608 elements
    cvt_fp32_bf16<<<8192, 256, 0, stream>>>(x, xb);
    // Pack combined transposed weight [Wq | Wkr | Wdkv | pad] -> WcatT (3712 x 2048)
    wtrans<<<dim3(96, 64), tb, 0, stream>>>(Wq, WcatT, 2048, 3072);
    wtrans<<<dim3(2, 64), tb, 0, stream>>>(Wkr, WcatT + (size_t)3072 * 2048, 2048, 64);
    wtrans<<<dim3(16, 64), tb, 0, stream>>>(Wdkv, WcatT + (size_t)3136 * 2048, 2048, 512);
    zerofill<<<512, 256, 0, stream>>>(WcatT + (size_t)3648 * 2048);
    wtrans<<<dim3(128, 16), tb, 0, stream>>>(Wukv, WukvT, 512, 4096);

    // XW = x @ [Wq|Wkr|Wdkv]   (4096 x 3712, K=2048)
    gemm_bt<bf16><<<dim3(29, 32), 256, 0, stream>>>(xb, 2048, WcatT, 2048, XW, 3712, 2048);
    // RoPE in-place on q_rope + k_rope columns
    rope_kernel<<<dim3(17, 1024), dim3(64, 4), 0, stream>>>(XW);
    // kv = c_kv @ Wukv (4096 x 4096, K=512), split epilogue -> kbuf + vT
    // (kbuf overwrites xb: dead after XW gemm; vT overwrites WcatT: dead too)
    gemm_kv<<<dim3(32, 32), 256, 0, stream>>>(XW + 3136, 3712, WukvT, 512, kbuf, vT, 512);
    // flash attention (attn_out overwrites WukvT slot: dead after gemm_kv)
    attn_kernel<<<dim3(32, 32), 256, 0, stream>>>(XW, kbuf, vT, attn_out);
    // WoT transposed after attn (vT slot free now)
    wtrans<<<dim3(64, 64), tb, 0, stream>>>(Wo, WoT, 2048, 2048);
    // out = attn_out @ Wo   (4096 x 2048, K=2048) -> fp32 output
    gemm_bt<float><<<dim3(16, 32), 256, 0, stream>>>(attn_out, 2048, WoT, 2048, out, 2048, 2048);
}

// Round 5
// 831.031 us; speedup vs baseline: 1.1837x; 1.1837x over previous
//
#include <hip/hip_runtime.h>
#include <hip/hip_bf16.h>

using bf16 = __hip_bfloat16;
typedef __bf16 bf16x8 __attribute__((ext_vector_type(8)));
typedef float f32x4 __attribute__((ext_vector_type(4)));

#define MFMA16(A, B, C) __builtin_amdgcn_mfma_f32_16x16x32_bf16((A), (B), (C), 0, 0, 0)

__device__ __forceinline__ void store_elem(bf16* p, float v) { *p = __float2bfloat16(v); }
__device__ __forceinline__ void store_elem(float* p, float v) { *p = v; }

// async global->LDS 16B per lane; LDS dest = wave-uniform base + lane*16.
__device__ __forceinline__ void async_cp16(const bf16* g, bf16* l) {
    __builtin_amdgcn_global_load_lds(
        (const __attribute__((address_space(1))) void*)g,
        (__attribute__((address_space(3))) void*)l, 16, 0, 0);
}

// ---------------------------------------------------------------------------
// fp32 -> bf16 convert, 4 elems/thread.
// ---------------------------------------------------------------------------
__global__ void cvt_fp32_bf16(const float* __restrict__ src, bf16* __restrict__ dst) {
    int i = (blockIdx.x * 256 + threadIdx.x) * 4;
    float4 v = *(const float4*)(src + i);
    bf16 o[4] = {__float2bfloat16(v.x), __float2bfloat16(v.y),
                 __float2bfloat16(v.z), __float2bfloat16(v.w)};
    *(uint2*)(dst + i) = *(const uint2*)o;
}

// ---------------------------------------------------------------------------
// Weight transpose + convert: src K x N fp32 -> dst N x K bf16.
// grid (N/32, K/32), block (32,8).
// ---------------------------------------------------------------------------
__global__ void wtrans(const float* __restrict__ src, bf16* __restrict__ dst,
                       int K, int N) {
    __shared__ bf16 t[32][33];
    int n0 = blockIdx.x * 32, k0 = blockIdx.y * 32;
    #pragma unroll
    for (int i = 0; i < 4; ++i) {
        int r = threadIdx.y + i * 8;
        t[r][threadIdx.x] = __float2bfloat16(src[(size_t)(k0 + r) * N + n0 + threadIdx.x]);
    }
    __syncthreads();
    #pragma unroll
    for (int i = 0; i < 4; ++i) {
        int r = threadIdx.y + i * 8;
        dst[(size_t)(n0 + r) * K + k0 + threadIdx.x] = t[threadIdx.x][r];
    }
}

__global__ void zerofill(bf16* __restrict__ p) {
    p[blockIdx.x * 256 + threadIdx.x] = __float2bfloat16(0.0f);
}

// ---------------------------------------------------------------------------
// GEMM: C[M][N] = A[M][K] @ Bt[N][K]^T. global_load_lds staging (m97 pattern).
// 128x128 tile, BK=32, 256 threads (4 waves). grid (N/128, M/128).
// ---------------------------------------------------------------------------
template <typename CT>
__global__ __launch_bounds__(256) void gemm_bt(
    const bf16* __restrict__ A, int lda,
    const bf16* __restrict__ Bt, int ldb,
    CT* __restrict__ C, int ldc, int K) {
    __shared__ bf16 As[128 * 32];
    __shared__ bf16 Bs[128 * 32];
    const int m0 = blockIdx.y * 128;
    const int n0 = blockIdx.x * 128;
    const int tid = threadIdx.x;
    const int lane = tid & 63;
    const int wave = tid >> 6;
    const int wm = (wave >> 1) * 64;
    const int wn = (wave & 1) * 64;
    const int lr = lane & 15;
    const int lq = lane >> 4;
    const int sr = tid >> 2;        // staging row 0..63
    const int sc = (tid & 3) * 8;   // staging col 0,8,16,24
    const int wbase = wave * 512;   // LDS elems: As + wbase + lane*8 == As + tid*8

    f32x4 acc[4][4] = {};

    for (int k0 = 0; k0 < K; k0 += 32) {
        __syncthreads();
        async_cp16(A + (size_t)(m0 + sr) * lda + k0 + sc, As + wbase);
        async_cp16(A + (size_t)(m0 + sr + 64) * lda + k0 + sc, As + 2048 + wbase);
        async_cp16(Bt + (size_t)(n0 + sr) * ldb + k0 + sc, Bs + wbase);
        async_cp16(Bt + (size_t)(n0 + sr + 64) * ldb + k0 + sc, Bs + 2048 + wbase);
        __syncthreads();
        bf16x8 af[4], bfr[4];
        #pragma unroll
        for (int t = 0; t < 4; ++t) {
            af[t]  = *(const bf16x8*)(As + (wm + t * 16 + lr) * 32 + lq * 8);
            bfr[t] = *(const bf16x8*)(Bs + (wn + t * 16 + lr) * 32 + lq * 8);
        }
        #pragma unroll
        for (int mt = 0; mt < 4; ++mt)
            #pragma unroll
            for (int nt = 0; nt < 4; ++nt)
                acc[mt][nt] = MFMA16(af[mt], bfr[nt], acc[mt][nt]);
    }
    #pragma unroll
    for (int mt = 0; mt < 4; ++mt)
        #pragma unroll
        for (int nt = 0; nt < 4; ++nt)
            #pragma unroll
            for (int r = 0; r < 4; ++r) {
                int row = m0 + wm + mt * 16 + lq * 4 + r;
                int col = n0 + wn + nt * 16 + lr;
                store_elem(C + (size_t)row * ldc + col, acc[mt][nt][r]);
            }
}

// ---------------------------------------------------------------------------
// kv GEMM, split epilogue: k_nope -> kbuf[row][h*128+r], v -> vT (transposed).
// grid (32, 32), K=512.
// ---------------------------------------------------------------------------
__global__ __launch_bounds__(256) void gemm_kv(
    const bf16* __restrict__ A, int lda,
    const bf16* __restrict__ Bt, int ldb,
    bf16* __restrict__ kbuf, bf16* __restrict__ vT, int K) {
    __shared__ bf16 As[128 * 32];
    __shared__ bf16 Bs[128 * 32];
    const int m0 = blockIdx.y * 128;
    const int n0 = blockIdx.x * 128;
    const int tid = threadIdx.x;
    const int lane = tid & 63;
    const int wave = tid >> 6;
    const int wm = (wave >> 1) * 64;
    const int wn = (wave & 1) * 64;
    const int lr = lane & 15;
    const int lq = lane >> 4;
    const int sr = tid >> 2;
    const int sc = (tid & 3) * 8;
    const int wbase = wave * 512;

    f32x4 acc[4][4] = {};

    for (int k0 = 0; k0 < K; k0 += 32) {
        __syncthreads();
        async_cp16(A + (size_t)(m0 + sr) * lda + k0 + sc, As + wbase);
        async_cp16(A + (size_t)(m0 + sr + 64) * lda + k0 + sc, As + 2048 + wbase);
        async_cp16(Bt + (size_t)(n0 + sr) * ldb + k0 + sc, Bs + wbase);
        async_cp16(Bt + (size_t)(n0 + sr + 64) * ldb + k0 + sc, Bs + 2048 + wbase);
        __syncthreads();
        bf16x8 af[4], bfr[4];
        #pragma unroll
        for (int t = 0; t < 4; ++t) {
            af[t]  = *(const bf16x8*)(As + (wm + t * 16 + lr) * 32 + lq * 8);
            bfr[t] = *(const bf16x8*)(Bs + (wn + t * 16 + lr) * 32 + lq * 8);
        }
        #pragma unroll
        for (int mt = 0; mt < 4; ++mt)
            #pragma unroll
            for (int nt = 0; nt < 4; ++nt)
                acc[mt][nt] = MFMA16(af[mt], bfr[nt], acc[mt][nt]);
    }
    #pragma unroll
    for (int mt = 0; mt < 4; ++mt)
        #pragma unroll
        for (int nt = 0; nt < 4; ++nt) {
            int colbase = n0 + wn + nt * 16;
            int h = colbase >> 8;
            int rr = (colbase & 255) + lr;
            #pragma unroll
            for (int r = 0; r < 4; ++r) {
                int row = m0 + wm + mt * 16 + lq * 4 + r;
                bf16 val = __float2bfloat16(acc[mt][nt][r]);
                if (rr < 128) {
                    kbuf[(size_t)row * 2048 + h * 128 + rr] = val;
                } else {
                    int dv = rr - 128;
                    int b = row >> 11, s = row & 2047;
                    vT[((size_t)((b * 16 + h) * 128 + dv)) * 2048 + s] = val;
                }
            }
        }
}

// ---------------------------------------------------------------------------
// RoPE in-place on XW[4096][3712]. grid (17, 1024), block (64,4).
// ---------------------------------------------------------------------------
__global__ void rope_kernel(bf16* __restrict__ XW) {
    int v = blockIdx.x;
    int row = blockIdx.y * 4 + threadIdx.y;
    int i = threadIdx.x;
    int s = row & 2047;
    int cbase = (v < 16) ? v * 192 + 128 : 3072;
    size_t base = (size_t)row * 3712 + cbase;
    float xi = __bfloat162float(XW[base + i]);
    float xp = __shfl_xor(xi, 32);
    int j = i & 31;
    float inv = exp2f(-(float)j * (13.287712379549449f / 32.0f));
    float ang = (float)s * inv;
    float c = cosf(ang), sn = sinf(ang);
    float res = (i < 32) ? (xi * c - xp * sn) : (xi * c + xp * sn);
    XW[base + i] = __float2bfloat16(res);
}

// ---------------------------------------------------------------------------
// Flash attention (causal), LDS-staged K/V shared by 4 waves.
// grid (16 qblocks, 32 bh), block 256. Block: 128 q rows; wave: 32 q rows.
// Key tiles of 64. Ks 64x(192 pad 200); Vs 128x(64 pad 72); Ps 32x72 per wave.
// ---------------------------------------------------------------------------
__global__ __launch_bounds__(256) void attn_kernel(
    const bf16* __restrict__ XW, const bf16* __restrict__ kbuf,
    const bf16* __restrict__ vT, bf16* __restrict__ attn_out) {
    const int bh = blockIdx.y, b = bh >> 4, h = bh & 15;
    const int tid = threadIdx.x;
    const int wave = tid >> 6;
    const int lane = tid & 63;
    const int lr = lane & 15, lq = lane >> 4;
    const int qb = blockIdx.x * 128;
    const int qw = qb + wave * 32;

    __shared__ bf16 Ks[64 * 200];
    __shared__ bf16 Vs[128 * 72];
    __shared__ bf16 Ps[4][32 * 72];

    const bf16* xwb = XW + (size_t)b * 2048 * 3712;
    const bf16* kb  = kbuf + (size_t)b * 2048 * 2048;
    const bf16* vTb = vT + (size_t)bh * 128 * 2048;

    // Q fragments: 2 m-frags x 6 chunks of 32
    bf16x8 qf[2][6];
    #pragma unroll
    for (int mf = 0; mf < 2; ++mf) {
        size_t ro = (size_t)(qw + mf * 16 + lr) * 3712 + h * 192;
        #pragma unroll
        for (int c = 0; c < 6; ++c)
            qf[mf][c] = *(const bf16x8*)(xwb + ro + c * 32 + lq * 8);
    }

    f32x4 o[2][8] = {};
    float m_i[2][4], l_i[2][4];
    #pragma unroll
    for (int mf = 0; mf < 2; ++mf)
        #pragma unroll
        for (int r = 0; r < 4; ++r) { m_i[mf][r] = -1e30f; l_i[mf][r] = 0.0f; }

    const float scale = 0.07216878364870323f;  // 1/sqrt(192)
    const float LOG2E = 1.4426950408889634f;

    const int krow = tid >> 2, kcg = tid & 3;   // K staging: 64 rows x 4 groups
    const int vrow = tid >> 1, vcg = tid & 1;   // V staging: 128 rows x 2 groups
    const int nend = qb + 128;

    for (int n0 = 0; n0 < nend; n0 += 64) {
        // prefetch to regs (overlaps previous tile's compute)
        uint4 kn[4], krp[2], vv[4];
        const bf16* kr = kb + (size_t)(n0 + krow) * 2048 + h * 128 + kcg * 32;
        #pragma unroll
        for (int i = 0; i < 4; ++i) kn[i] = *(const uint4*)(kr + i * 8);
        const bf16* xr = xwb + (size_t)(n0 + krow) * 3712 + 3072 + kcg * 16;
        krp[0] = *(const uint4*)(xr);
        krp[1] = *(const uint4*)(xr + 8);
        const bf16* vr = vTb + (size_t)vrow * 2048 + n0 + vcg * 32;
        #pragma unroll
        for (int i = 0; i < 4; ++i) vv[i] = *(const uint4*)(vr + i * 8);
        __syncthreads();
        #pragma unroll
        for (int i = 0; i < 4; ++i)
            *(uint4*)(Ks + krow * 200 + kcg * 32 + i * 8) = kn[i];
        *(uint4*)(Ks + krow * 200 + 128 + kcg * 16) = krp[0];
        *(uint4*)(Ks + krow * 200 + 128 + kcg * 16 + 8) = krp[1];
        #pragma unroll
        for (int i = 0; i < 4; ++i)
            *(uint4*)(Vs + vrow * 72 + vcg * 32 + i * 8) = vv[i];
        __syncthreads();

        if (n0 < qw + 32) {  // wave-uniform: skip fully-masked tiles
            // ---- QK^T: 48 MFMAs ----
            f32x4 s[2][4] = {};
            #pragma unroll
            for (int c = 0; c < 6; ++c)
                #pragma unroll
                for (int nt = 0; nt < 4; ++nt) {
                    bf16x8 kf = *(const bf16x8*)(Ks + (nt * 16 + lr) * 200 + c * 32 + lq * 8);
                    s[0][nt] = MFMA16(qf[0][c], kf, s[0][nt]);
                    s[1][nt] = MFMA16(qf[1][c], kf, s[1][nt]);
                }
            // ---- online softmax (one update per 64-key tile) ----
            #pragma unroll
            for (int mf = 0; mf < 2; ++mf)
                #pragma unroll
                for (int r = 0; r < 4; ++r) {
                    int qrow = qw + mf * 16 + lq * 4 + r;
                    float a[4];
                    #pragma unroll
                    for (int nt = 0; nt < 4; ++nt) {
                        int key = n0 + nt * 16 + lr;
                        a[nt] = (key <= qrow) ? s[mf][nt][r] * scale : -1e30f;
                    }
                    float t = fmaxf(fmaxf(a[0], a[1]), fmaxf(a[2], a[3]));
                    #pragma unroll
                    for (int off = 1; off < 16; off <<= 1) t = fmaxf(t, __shfl_xor(t, off));
                    float mnew = fmaxf(m_i[mf][r], t);
                    float alpha = exp2f((m_i[mf][r] - mnew) * LOG2E);
                    m_i[mf][r] = mnew;
                    float p[4], ps = 0.0f;
                    #pragma unroll
                    for (int nt = 0; nt < 4; ++nt) {
                        p[nt] = exp2f((a[nt] - mnew) * LOG2E);
                        ps += p[nt];
                    }
                    #pragma unroll
                    for (int off = 1; off < 16; off <<= 1) ps += __shfl_xor(ps, off);
                    l_i[mf][r] = l_i[mf][r] * alpha + ps;
                    #pragma unroll
                    for (int dt = 0; dt < 8; ++dt) o[mf][dt][r] *= alpha;
                    int prow = mf * 16 + lq * 4 + r;
                    #pragma unroll
                    for (int nt = 0; nt < 4; ++nt)
                        Ps[wave][prow * 72 + nt * 16 + lr] = __float2bfloat16(p[nt]);
                }
            // in-wave LDS RAW: wait for ds_writes before cross-lane reads
            __asm__ volatile("s_waitcnt lgkmcnt(0)" ::: "memory");
            bf16x8 pf[2][2];
            #pragma unroll
            for (int mf = 0; mf < 2; ++mf)
                #pragma unroll
                for (int kt = 0; kt < 2; ++kt)
                    pf[mf][kt] = *(const bf16x8*)(&Ps[wave][(mf * 16 + lr) * 72 + kt * 32 + lq * 8]);
            // ---- PV: 32 MFMAs ----
            #pragma unroll
            for (int kt = 0; kt < 2; ++kt)
                #pragma unroll
                for (int dt = 0; dt < 8; ++dt) {
                    bf16x8 vf = *(const bf16x8*)(Vs + (dt * 16 + lr) * 72 + kt * 32 + lq * 8);
                    o[0][dt] = MFMA16(pf[0][kt], vf, o[0][dt]);
                    o[1][dt] = MFMA16(pf[1][kt], vf, o[1][dt]);
                }
        }
    }
    #pragma unroll
    for (int mf = 0; mf < 2; ++mf)
        #pragma unroll
        for (int r = 0; r < 4; ++r) {
            float invl = 1.0f / l_i[mf][r];
            int qrow = qw + mf * 16 + lq * 4 + r;
            size_t orow = (size_t)(b * 2048 + qrow) * 2048 + h * 128;
            #pragma unroll
            for (int dt = 0; dt < 8; ++dt)
                attn_out[orow + dt * 16 + lr] = __float2bfloat16(o[mf][dt][r] * invl);
        }
}

// ---------------------------------------------------------------------------
extern "C" void kernel_launch(void* const* d_in, const int* in_sizes, int n_in,
                              void* d_out, int out_size, void* d_ws, size_t ws_size,
                              hipStream_t stream) {
    const float* x    = (const float*)d_in[0];
    const float* Wq   = (const float*)d_in[1];
    const float* Wdkv = (const float*)d_in[2];
    const float* Wkr  = (const float*)d_in[3];
    const float* Wukv = (const float*)d_in[4];
    const float* Wo   = (const float*)d_in[5];
    float* out = (float*)d_out;  // reference output dtype is float32

    // Workspace layout (80,740,352 bytes), time-sliced aliasing (see r1-r3).
    char* ws = (char*)d_ws;
    bf16* XW       = (bf16*)(ws);
    bf16* kbuf     = (bf16*)(ws + 30408704);
    bf16* vT       = (bf16*)(ws + 47185920);
    bf16* attn_out = (bf16*)(ws + 63963136);
    bf16* xb       = (bf16*)(ws + 30408704);  // alias kbuf
    bf16* WcatT    = (bf16*)(ws + 47185920);  // alias vT
    bf16* WukvT    = (bf16*)(ws + 63963136);  // alias attn_out
    bf16* WoT      = (bf16*)(ws + 47185920);  // alias vT (after attn)

    dim3 tb(32, 8);
    cvt_fp32_bf16<<<8192, 256, 0, stream>>>(x, xb);
    wtrans<<<dim3(96, 64), tb, 0, stream>>>(Wq, WcatT, 2048, 3072);
    wtrans<<<dim3(2, 64), tb, 0, stream>>>(Wkr, WcatT + (size_t)3072 * 2048, 2048, 64);
    wtrans<<<dim3(16, 64), tb, 0, stream>>>(Wdkv, WcatT + (size_t)3136 * 2048, 2048, 512);
    zerofill<<<512, 256, 0, stream>>>(WcatT + (size_t)3648 * 2048);
    wtrans<<<dim3(128, 16), tb, 0, stream>>>(Wukv, WukvT, 512, 4096);

    // XW = x @ [Wq|Wkr|Wdkv]   (4096 x 3712, K=2048)
    gemm_bt<bf16><<<dim3(29, 32), 256, 0, stream>>>(xb, 2048, WcatT, 2048, XW, 3712, 2048);
    rope_kernel<<<dim3(17, 1024), dim3(64, 4), 0, stream>>>(XW);
    // kv = c_kv @ Wukv (4096 x 4096, K=512) -> kbuf + vT
    gemm_kv<<<dim3(32, 32), 256, 0, stream>>>(XW + 3136, 3712, WukvT, 512, kbuf, vT, 512);
    // flash attention: 128 q rows/block
    attn_kernel<<<dim3(16, 32), 256, 0, stream>>>(XW, kbuf, vT, attn_out);
    wtrans<<<dim3(64, 64), tb, 0, stream>>>(Wo, WoT, 2048, 2048);
    // out = attn_out @ Wo   (4096 x 2048, K=2048) -> fp32
    gemm_bt<float><<<dim3(16, 32), 256, 0, stream>>>(attn_out, 2048, WoT, 2048, out, 2048, 2048);
}

// Round 6
// 768.405 us; speedup vs baseline: 1.2801x; 1.0815x over previous
//
#include <hip/hip_runtime.h>
#include <hip/hip_bf16.h>

using bf16 = __hip_bfloat16;
typedef __bf16 bf16x8 __attribute__((ext_vector_type(8)));
typedef float f32x4 __attribute__((ext_vector_type(4)));

#define MFMA16(A, B, C) __builtin_amdgcn_mfma_f32_16x16x32_bf16((A), (B), (C), 0, 0, 0)

__device__ __forceinline__ void store_elem(bf16* p, float v) { *p = __float2bfloat16(v); }
__device__ __forceinline__ void store_elem(float* p, float v) { *p = v; }

// async global->LDS 16B per lane; LDS dest = wave-uniform base + lane*16.
__device__ __forceinline__ void async_cp16(const bf16* g, bf16* l) {
    __builtin_amdgcn_global_load_lds(
        (const __attribute__((address_space(1))) void*)g,
        (__attribute__((address_space(3))) void*)l, 16, 0, 0);
}

// ---------------------------------------------------------------------------
__global__ void cvt_fp32_bf16(const float* __restrict__ src, bf16* __restrict__ dst) {
    int i = (blockIdx.x * 256 + threadIdx.x) * 4;
    float4 v = *(const float4*)(src + i);
    bf16 o[4] = {__float2bfloat16(v.x), __float2bfloat16(v.y),
                 __float2bfloat16(v.z), __float2bfloat16(v.w)};
    *(uint2*)(dst + i) = *(const uint2*)o;
}

// ---------------------------------------------------------------------------
__global__ void wtrans(const float* __restrict__ src, bf16* __restrict__ dst,
                       int K, int N) {
    __shared__ bf16 t[32][33];
    int n0 = blockIdx.x * 32, k0 = blockIdx.y * 32;
    #pragma unroll
    for (int i = 0; i < 4; ++i) {
        int r = threadIdx.y + i * 8;
        t[r][threadIdx.x] = __float2bfloat16(src[(size_t)(k0 + r) * N + n0 + threadIdx.x]);
    }
    __syncthreads();
    #pragma unroll
    for (int i = 0; i < 4; ++i) {
        int r = threadIdx.y + i * 8;
        dst[(size_t)(n0 + r) * K + k0 + threadIdx.x] = t[threadIdx.x][r];
    }
}

__global__ void zerofill(bf16* __restrict__ p) {
    p[blockIdx.x * 256 + threadIdx.x] = __float2bfloat16(0.0f);
}

// ---------------------------------------------------------------------------
// GEMM: C[M][N] = A[M][K] @ Bt[N][K]^T. global_load_lds staging (m97 pattern).
// ---------------------------------------------------------------------------
template <typename CT>
__global__ __launch_bounds__(256) void gemm_bt(
    const bf16* __restrict__ A, int lda,
    const bf16* __restrict__ Bt, int ldb,
    CT* __restrict__ C, int ldc, int K) {
    __shared__ bf16 As[128 * 32];
    __shared__ bf16 Bs[128 * 32];
    const int m0 = blockIdx.y * 128;
    const int n0 = blockIdx.x * 128;
    const int tid = threadIdx.x;
    const int lane = tid & 63;
    const int wave = tid >> 6;
    const int wm = (wave >> 1) * 64;
    const int wn = (wave & 1) * 64;
    const int lr = lane & 15;
    const int lq = lane >> 4;
    const int sr = tid >> 2;
    const int sc = (tid & 3) * 8;
    const int wbase = wave * 512;

    f32x4 acc[4][4] = {};

    for (int k0 = 0; k0 < K; k0 += 32) {
        __syncthreads();
        async_cp16(A + (size_t)(m0 + sr) * lda + k0 + sc, As + wbase);
        async_cp16(A + (size_t)(m0 + sr + 64) * lda + k0 + sc, As + 2048 + wbase);
        async_cp16(Bt + (size_t)(n0 + sr) * ldb + k0 + sc, Bs + wbase);
        async_cp16(Bt + (size_t)(n0 + sr + 64) * ldb + k0 + sc, Bs + 2048 + wbase);
        __syncthreads();
        bf16x8 af[4], bfr[4];
        #pragma unroll
        for (int t = 0; t < 4; ++t) {
            af[t]  = *(const bf16x8*)(As + (wm + t * 16 + lr) * 32 + lq * 8);
            bfr[t] = *(const bf16x8*)(Bs + (wn + t * 16 + lr) * 32 + lq * 8);
        }
        #pragma unroll
        for (int mt = 0; mt < 4; ++mt)
            #pragma unroll
            for (int nt = 0; nt < 4; ++nt)
                acc[mt][nt] = MFMA16(af[mt], bfr[nt], acc[mt][nt]);
    }
    #pragma unroll
    for (int mt = 0; mt < 4; ++mt)
        #pragma unroll
        for (int nt = 0; nt < 4; ++nt)
            #pragma unroll
            for (int r = 0; r < 4; ++r) {
                int row = m0 + wm + mt * 16 + lq * 4 + r;
                int col = n0 + wn + nt * 16 + lr;
                store_elem(C + (size_t)row * ldc + col, acc[mt][nt][r]);
            }
}

// ---------------------------------------------------------------------------
// kv GEMM, split epilogue: k_nope -> kbuf, v -> vT (transposed). grid (32,32).
// ---------------------------------------------------------------------------
__global__ __launch_bounds__(256) void gemm_kv(
    const bf16* __restrict__ A, int lda,
    const bf16* __restrict__ Bt, int ldb,
    bf16* __restrict__ kbuf, bf16* __restrict__ vT, int K) {
    __shared__ bf16 As[128 * 32];
    __shared__ bf16 Bs[128 * 32];
    const int m0 = blockIdx.y * 128;
    const int n0 = blockIdx.x * 128;
    const int tid = threadIdx.x;
    const int lane = tid & 63;
    const int wave = tid >> 6;
    const int wm = (wave >> 1) * 64;
    const int wn = (wave & 1) * 64;
    const int lr = lane & 15;
    const int lq = lane >> 4;
    const int sr = tid >> 2;
    const int sc = (tid & 3) * 8;
    const int wbase = wave * 512;

    f32x4 acc[4][4] = {};

    for (int k0 = 0; k0 < K; k0 += 32) {
        __syncthreads();
        async_cp16(A + (size_t)(m0 + sr) * lda + k0 + sc, As + wbase);
        async_cp16(A + (size_t)(m0 + sr + 64) * lda + k0 + sc, As + 2048 + wbase);
        async_cp16(Bt + (size_t)(n0 + sr) * ldb + k0 + sc, Bs + wbase);
        async_cp16(Bt + (size_t)(n0 + sr + 64) * ldb + k0 + sc, Bs + 2048 + wbase);
        __syncthreads();
        bf16x8 af[4], bfr[4];
        #pragma unroll
        for (int t = 0; t < 4; ++t) {
            af[t]  = *(const bf16x8*)(As + (wm + t * 16 + lr) * 32 + lq * 8);
            bfr[t] = *(const bf16x8*)(Bs + (wn + t * 16 + lr) * 32 + lq * 8);
        }
        #pragma unroll
        for (int mt = 0; mt < 4; ++mt)
            #pragma unroll
            for (int nt = 0; nt < 4; ++nt)
                acc[mt][nt] = MFMA16(af[mt], bfr[nt], acc[mt][nt]);
    }
    #pragma unroll
    for (int mt = 0; mt < 4; ++mt)
        #pragma unroll
        for (int nt = 0; nt < 4; ++nt) {
            int colbase = n0 + wn + nt * 16;
            int h = colbase >> 8;
            int rr = (colbase & 255) + lr;
            #pragma unroll
            for (int r = 0; r < 4; ++r) {
                int row = m0 + wm + mt * 16 + lq * 4 + r;
                bf16 val = __float2bfloat16(acc[mt][nt][r]);
                if (rr < 128) {
                    kbuf[(size_t)row * 2048 + h * 128 + rr] = val;
                } else {
                    int dv = rr - 128;
                    int b = row >> 11, s = row & 2047;
                    vT[((size_t)((b * 16 + h) * 128 + dv)) * 2048 + s] = val;
                }
            }
        }
}

// ---------------------------------------------------------------------------
__global__ void rope_kernel(bf16* __restrict__ XW) {
    int v = blockIdx.x;
    int row = blockIdx.y * 4 + threadIdx.y;
    int i = threadIdx.x;
    int s = row & 2047;
    int cbase = (v < 16) ? v * 192 + 128 : 3072;
    size_t base = (size_t)row * 3712 + cbase;
    float xi = __bfloat162float(XW[base + i]);
    float xp = __shfl_xor(xi, 32);
    int j = i & 31;
    float inv = exp2f(-(float)j * (13.287712379549449f / 32.0f));
    float ang = (float)s * inv;
    float c = cosf(ang), sn = sinf(ang);
    float res = (i < 32) ? (xi * c - xp * sn) : (xi * c + xp * sn);
    XW[base + i] = __float2bfloat16(res);
}

// ---------------------------------------------------------------------------
// Flash attention pass 1 (causal), split-K for load balance.
// grid (24, 32 bh), block 256 (4 waves, each 32 q rows).
// bx<8:  qt=bx,   keys [0,(qt+1)*128)     -> final attn_out (q rows < 1024)
// 8<=bx<16: qt=bx, keys [0,1024)          -> partial chunk 0
// bx>=16: qt=bx-8, keys [1024,(qt+1)*128) -> partial chunk 1
// Partials: opart bf16 [b][urow][ck][16*128], ml fp32 [b][urow][ck][h][2].
// ---------------------------------------------------------------------------
__global__ __launch_bounds__(256) void attn_kernel(
    const bf16* __restrict__ XW, const bf16* __restrict__ kbuf,
    const bf16* __restrict__ vT, bf16* __restrict__ attn_out,
    bf16* __restrict__ opart, float* __restrict__ mlbuf) {
    const int bh = blockIdx.y, b = bh >> 4, h = bh & 15;
    const int bx = blockIdx.x;
    int qt, ck, ks, ke;
    bool partial;
    if (bx < 8)       { qt = bx;     ck = 0; partial = false; ks = 0;    ke = (qt + 1) * 128; }
    else if (bx < 16) { qt = bx;     ck = 0; partial = true;  ks = 0;    ke = 1024; }
    else              { qt = bx - 8; ck = 1; partial = true;  ks = 1024; ke = (qt + 1) * 128; }

    const int tid = threadIdx.x;
    const int wave = tid >> 6;
    const int lane = tid & 63;
    const int lr = lane & 15, lq = lane >> 4;
    const int qw = qt * 128 + wave * 32;

    __shared__ bf16 Ks[64 * 200];
    __shared__ bf16 Vs[128 * 72];
    __shared__ bf16 Ps[4][32 * 72];

    const bf16* xwb = XW + (size_t)b * 2048 * 3712;
    const bf16* kb  = kbuf + (size_t)b * 2048 * 2048;
    const bf16* vTb = vT + (size_t)bh * 128 * 2048;

    bf16x8 qf[2][6];
    #pragma unroll
    for (int mf = 0; mf < 2; ++mf) {
        size_t ro = (size_t)(qw + mf * 16 + lr) * 3712 + h * 192;
        #pragma unroll
        for (int c = 0; c < 6; ++c)
            qf[mf][c] = *(const bf16x8*)(xwb + ro + c * 32 + lq * 8);
    }

    f32x4 o[2][8] = {};
    float m_i[2][4], l_i[2][4];
    #pragma unroll
    for (int mf = 0; mf < 2; ++mf)
        #pragma unroll
        for (int r = 0; r < 4; ++r) { m_i[mf][r] = -1e30f; l_i[mf][r] = 0.0f; }

    const float scale = 0.07216878364870323f;  // 1/sqrt(192)
    const float LOG2E = 1.4426950408889634f;

    const int krow = tid >> 2, kcg = tid & 3;
    const int vrow = tid >> 1, vcg = tid & 1;

    for (int n0 = ks; n0 < ke; n0 += 64) {
        uint4 kn[4], krp[2], vv[4];
        const bf16* kr = kb + (size_t)(n0 + krow) * 2048 + h * 128 + kcg * 32;
        #pragma unroll
        for (int i = 0; i < 4; ++i) kn[i] = *(const uint4*)(kr + i * 8);
        const bf16* xr = xwb + (size_t)(n0 + krow) * 3712 + 3072 + kcg * 16;
        krp[0] = *(const uint4*)(xr);
        krp[1] = *(const uint4*)(xr + 8);
        const bf16* vr = vTb + (size_t)vrow * 2048 + n0 + vcg * 32;
        #pragma unroll
        for (int i = 0; i < 4; ++i) vv[i] = *(const uint4*)(vr + i * 8);
        __syncthreads();
        #pragma unroll
        for (int i = 0; i < 4; ++i)
            *(uint4*)(Ks + krow * 200 + kcg * 32 + i * 8) = kn[i];
        *(uint4*)(Ks + krow * 200 + 128 + kcg * 16) = krp[0];
        *(uint4*)(Ks + krow * 200 + 128 + kcg * 16 + 8) = krp[1];
        #pragma unroll
        for (int i = 0; i < 4; ++i)
            *(uint4*)(Vs + vrow * 72 + vcg * 32 + i * 8) = vv[i];
        __syncthreads();

        if (n0 < qw + 32) {  // wave-uniform: skip fully-masked tiles
            f32x4 s[2][4] = {};
            #pragma unroll
            for (int c = 0; c < 6; ++c)
                #pragma unroll
                for (int nt = 0; nt < 4; ++nt) {
                    bf16x8 kf = *(const bf16x8*)(Ks + (nt * 16 + lr) * 200 + c * 32 + lq * 8);
                    s[0][nt] = MFMA16(qf[0][c], kf, s[0][nt]);
                    s[1][nt] = MFMA16(qf[1][c], kf, s[1][nt]);
                }
            #pragma unroll
            for (int mf = 0; mf < 2; ++mf)
                #pragma unroll
                for (int r = 0; r < 4; ++r) {
                    int qrow = qw + mf * 16 + lq * 4 + r;
                    float a[4];
                    #pragma unroll
                    for (int nt = 0; nt < 4; ++nt) {
                        int key = n0 + nt * 16 + lr;
                        a[nt] = (key <= qrow) ? s[mf][nt][r] * scale : -1e30f;
                    }
                    float t = fmaxf(fmaxf(a[0], a[1]), fmaxf(a[2], a[3]));
                    #pragma unroll
                    for (int off = 1; off < 16; off <<= 1) t = fmaxf(t, __shfl_xor(t, off));
                    float mnew = fmaxf(m_i[mf][r], t);
                    float alpha = exp2f((m_i[mf][r] - mnew) * LOG2E);
                    m_i[mf][r] = mnew;
                    float p[4], ps = 0.0f;
                    #pragma unroll
                    for (int nt = 0; nt < 4; ++nt) {
                        p[nt] = exp2f((a[nt] - mnew) * LOG2E);
                        ps += p[nt];
                    }
                    #pragma unroll
                    for (int off = 1; off < 16; off <<= 1) ps += __shfl_xor(ps, off);
                    l_i[mf][r] = l_i[mf][r] * alpha + ps;
                    #pragma unroll
                    for (int dt = 0; dt < 8; ++dt) o[mf][dt][r] *= alpha;
                    int prow = mf * 16 + lq * 4 + r;
                    #pragma unroll
                    for (int nt = 0; nt < 4; ++nt)
                        Ps[wave][prow * 72 + nt * 16 + lr] = __float2bfloat16(p[nt]);
                }
            __asm__ volatile("s_waitcnt lgkmcnt(0)" ::: "memory");
            bf16x8 pf[2][2];
            #pragma unroll
            for (int mf = 0; mf < 2; ++mf)
                #pragma unroll
                for (int kt = 0; kt < 2; ++kt)
                    pf[mf][kt] = *(const bf16x8*)(&Ps[wave][(mf * 16 + lr) * 72 + kt * 32 + lq * 8]);
            #pragma unroll
            for (int kt = 0; kt < 2; ++kt)
                #pragma unroll
                for (int dt = 0; dt < 8; ++dt) {
                    bf16x8 vf = *(const bf16x8*)(Vs + (dt * 16 + lr) * 72 + kt * 32 + lq * 8);
                    o[0][dt] = MFMA16(pf[0][kt], vf, o[0][dt]);
                    o[1][dt] = MFMA16(pf[1][kt], vf, o[1][dt]);
                }
        }
    }
    if (!partial) {
        #pragma unroll
        for (int mf = 0; mf < 2; ++mf)
            #pragma unroll
            for (int r = 0; r < 4; ++r) {
                float invl = 1.0f / l_i[mf][r];
                int qrow = qw + mf * 16 + lq * 4 + r;
                size_t orow = (size_t)(b * 2048 + qrow) * 2048 + h * 128;
                #pragma unroll
                for (int dt = 0; dt < 8; ++dt)
                    attn_out[orow + dt * 16 + lr] = __float2bfloat16(o[mf][dt][r] * invl);
            }
    } else {
        #pragma unroll
        for (int mf = 0; mf < 2; ++mf)
            #pragma unroll
            for (int r = 0; r < 4; ++r) {
                int qrow = qw + mf * 16 + lq * 4 + r;
                int urow = qrow - 1024;
                size_t pb = ((size_t)((b * 1024 + urow) * 2 + ck)) * 2048 + h * 128;
                #pragma unroll
                for (int dt = 0; dt < 8; ++dt)
                    opart[pb + dt * 16 + lr] = __float2bfloat16(o[mf][dt][r]);
                if (lr == 0) {
                    float* mlp = mlbuf + (((size_t)((b * 1024 + urow) * 2 + ck)) * 16 + h) * 2;
                    mlp[0] = m_i[mf][r];
                    mlp[1] = l_i[mf][r];
                }
            }
    }
}

// ---------------------------------------------------------------------------
// Merge the two key-chunks for q rows >= 1024. grid (2048, 8), block (128,2).
// ---------------------------------------------------------------------------
__global__ void attn_merge(const bf16* __restrict__ opart,
                           const float* __restrict__ mlbuf,
                           bf16* __restrict__ attn_out) {
    int bu = blockIdx.x;            // b*1024 + urow
    int b = bu >> 10, urow = bu & 1023;
    int h = blockIdx.y * 2 + threadIdx.y;
    int tx = threadIdx.x;
    const float* mlp = mlbuf + (((size_t)bu * 2) * 16 + h) * 2;
    float m0 = mlp[0], l0 = mlp[1];
    float m1 = mlp[32], l1 = mlp[33];
    size_t ob = ((size_t)bu * 2) * 2048 + h * 128 + tx;
    float o0 = __bfloat162float(opart[ob]);
    float o1 = __bfloat162float(opart[ob + 2048]);
    float m = fmaxf(m0, m1);
    const float LOG2E = 1.4426950408889634f;
    float w0 = exp2f((m0 - m) * LOG2E);
    float w1 = exp2f((m1 - m) * LOG2E);
    float v = (o0 * w0 + o1 * w1) / (l0 * w0 + l1 * w1);
    attn_out[((size_t)(b * 2048 + 1024 + urow)) * 2048 + h * 128 + tx] = __float2bfloat16(v);
}

// ---------------------------------------------------------------------------
extern "C" void kernel_launch(void* const* d_in, const int* in_sizes, int n_in,
                              void* d_out, int out_size, void* d_ws, size_t ws_size,
                              hipStream_t stream) {
    const float* x    = (const float*)d_in[0];
    const float* Wq   = (const float*)d_in[1];
    const float* Wdkv = (const float*)d_in[2];
    const float* Wkr  = (const float*)d_in[3];
    const float* Wukv = (const float*)d_in[4];
    const float* Wo   = (const float*)d_in[5];
    float* out = (float*)d_out;

    // Workspace layout (98,041,856 bytes), time-sliced aliasing:
    //   XW @0 (30.4MB); kbuf @30,408,704 (16.8MB); vT @47,185,920 (16.8MB);
    //   attn_out @63,963,136 (16.8MB); opart @80,740,352 (16.8MB);
    //   ml @97,517,568 (0.5MB).
    //   xb aliases kbuf; WcatT aliases vT; WukvT aliases attn_out;
    //   WoT aliases vT (after attention pass 1).
    char* ws = (char*)d_ws;
    bf16* XW       = (bf16*)(ws);
    bf16* kbuf     = (bf16*)(ws + 30408704);
    bf16* vT       = (bf16*)(ws + 47185920);
    bf16* attn_out = (bf16*)(ws + 63963136);
    bf16* opart    = (bf16*)(ws + 80740352);
    float* mlbuf   = (float*)(ws + 97517568);
    bf16* xb       = (bf16*)(ws + 30408704);  // alias kbuf
    bf16* WcatT    = (bf16*)(ws + 47185920);  // alias vT
    bf16* WukvT    = (bf16*)(ws + 63963136);  // alias attn_out
    bf16* WoT      = (bf16*)(ws + 47185920);  // alias vT (after attn)

    dim3 tb(32, 8);
    cvt_fp32_bf16<<<8192, 256, 0, stream>>>(x, xb);
    wtrans<<<dim3(96, 64), tb, 0, stream>>>(Wq, WcatT, 2048, 3072);
    wtrans<<<dim3(2, 64), tb, 0, stream>>>(Wkr, WcatT + (size_t)3072 * 2048, 2048, 64);
    wtrans<<<dim3(16, 64), tb, 0, stream>>>(Wdkv, WcatT + (size_t)3136 * 2048, 2048, 512);
    zerofill<<<512, 256, 0, stream>>>(WcatT + (size_t)3648 * 2048);
    wtrans<<<dim3(128, 16), tb, 0, stream>>>(Wukv, WukvT, 512, 4096);

    gemm_bt<bf16><<<dim3(29, 32), 256, 0, stream>>>(xb, 2048, WcatT, 2048, XW, 3712, 2048);
    rope_kernel<<<dim3(17, 1024), dim3(64, 4), 0, stream>>>(XW);
    gemm_kv<<<dim3(32, 32), 256, 0, stream>>>(XW + 3136, 3712, WukvT, 512, kbuf, vT, 512);
    // split-K flash attention + merge
    attn_kernel<<<dim3(24, 32), 256, 0, stream>>>(XW, kbuf, vT, attn_out, opart, mlbuf);
    attn_merge<<<dim3(2048, 8), dim3(128, 2), 0, stream>>>(opart, mlbuf, attn_out);
    wtrans<<<dim3(64, 64), tb, 0, stream>>>(Wo, WoT, 2048, 2048);
    gemm_bt<float><<<dim3(16, 32), 256, 0, stream>>>(attn_out, 2048, WoT, 2048, out, 2048, 2048);
}

// Round 7
// 635.437 us; speedup vs baseline: 1.5480x; 1.2093x over previous
//
#include <hip/hip_runtime.h>
#include <hip/hip_bf16.h>

using bf16 = __hip_bfloat16;
typedef __bf16 bf16x8 __attribute__((ext_vector_type(8)));
typedef float f32x4 __attribute__((ext_vector_type(4)));

#define MFMA16(A, B, C) __builtin_amdgcn_mfma_f32_16x16x32_bf16((A), (B), (C), 0, 0, 0)

__device__ __forceinline__ void store_elem(bf16* p, float v) { *p = __float2bfloat16(v); }
__device__ __forceinline__ void store_elem(float* p, float v) { *p = v; }

__device__ __forceinline__ unsigned short f2bu(float x) {
    bf16 t = __float2bfloat16(x);
    return *(unsigned short*)&t;
}

// async global->LDS 16B per lane; LDS dest = wave-uniform base + lane*16.
__device__ __forceinline__ void async_cp16(const bf16* g, bf16* l) {
    __builtin_amdgcn_global_load_lds(
        (const __attribute__((address_space(1))) void*)g,
        (__attribute__((address_space(3))) void*)l, 16, 0, 0);
}

// ---------------------------------------------------------------------------
__global__ void cvt_fp32_bf16(const float* __restrict__ src, bf16* __restrict__ dst) {
    int i = (blockIdx.x * 256 + threadIdx.x) * 4;
    float4 v = *(const float4*)(src + i);
    bf16 o[4] = {__float2bfloat16(v.x), __float2bfloat16(v.y),
                 __float2bfloat16(v.z), __float2bfloat16(v.w)};
    *(uint2*)(dst + i) = *(const uint2*)o;
}

// ---------------------------------------------------------------------------
__global__ void wtrans(const float* __restrict__ src, bf16* __restrict__ dst,
                       int K, int N) {
    __shared__ bf16 t[32][33];
    int n0 = blockIdx.x * 32, k0 = blockIdx.y * 32;
    #pragma unroll
    for (int i = 0; i < 4; ++i) {
        int r = threadIdx.y + i * 8;
        t[r][threadIdx.x] = __float2bfloat16(src[(size_t)(k0 + r) * N + n0 + threadIdx.x]);
    }
    __syncthreads();
    #pragma unroll
    for (int i = 0; i < 4; ++i) {
        int r = threadIdx.y + i * 8;
        dst[(size_t)(n0 + r) * K + k0 + threadIdx.x] = t[threadIdx.x][r];
    }
}

__global__ void zerofill(bf16* __restrict__ p) {
    p[blockIdx.x * 256 + threadIdx.x] = __float2bfloat16(0.0f);
}

// ---------------------------------------------------------------------------
// GEMM: C[M][N] = A[M][K] @ Bt[N][K]^T. global_load_lds staging (m97 pattern).
// ---------------------------------------------------------------------------
template <typename CT>
__global__ __launch_bounds__(256) void gemm_bt(
    const bf16* __restrict__ A, int lda,
    const bf16* __restrict__ Bt, int ldb,
    CT* __restrict__ C, int ldc, int K) {
    __shared__ bf16 As[128 * 32];
    __shared__ bf16 Bs[128 * 32];
    const int m0 = blockIdx.y * 128;
    const int n0 = blockIdx.x * 128;
    const int tid = threadIdx.x;
    const int lane = tid & 63;
    const int wave = tid >> 6;
    const int wm = (wave >> 1) * 64;
    const int wn = (wave & 1) * 64;
    const int lr = lane & 15;
    const int lq = lane >> 4;
    const int sr = tid >> 2;
    const int sc = (tid & 3) * 8;
    const int wbase = wave * 512;

    f32x4 acc[4][4] = {};

    for (int k0 = 0; k0 < K; k0 += 32) {
        __syncthreads();
        async_cp16(A + (size_t)(m0 + sr) * lda + k0 + sc, As + wbase);
        async_cp16(A + (size_t)(m0 + sr + 64) * lda + k0 + sc, As + 2048 + wbase);
        async_cp16(Bt + (size_t)(n0 + sr) * ldb + k0 + sc, Bs + wbase);
        async_cp16(Bt + (size_t)(n0 + sr + 64) * ldb + k0 + sc, Bs + 2048 + wbase);
        __syncthreads();
        bf16x8 af[4], bfr[4];
        #pragma unroll
        for (int t = 0; t < 4; ++t) {
            af[t]  = *(const bf16x8*)(As + (wm + t * 16 + lr) * 32 + lq * 8);
            bfr[t] = *(const bf16x8*)(Bs + (wn + t * 16 + lr) * 32 + lq * 8);
        }
        #pragma unroll
        for (int mt = 0; mt < 4; ++mt)
            #pragma unroll
            for (int nt = 0; nt < 4; ++nt)
                acc[mt][nt] = MFMA16(af[mt], bfr[nt], acc[mt][nt]);
    }
    #pragma unroll
    for (int mt = 0; mt < 4; ++mt)
        #pragma unroll
        for (int nt = 0; nt < 4; ++nt)
            #pragma unroll
            for (int r = 0; r < 4; ++r) {
                int row = m0 + wm + mt * 16 + lq * 4 + r;
                int col = n0 + wn + nt * 16 + lr;
                store_elem(C + (size_t)row * ldc + col, acc[mt][nt][r]);
            }
}

// ---------------------------------------------------------------------------
// kv GEMM, split epilogue: k_nope -> kbuf, v -> vT (transposed). grid (32,32).
// ---------------------------------------------------------------------------
__global__ __launch_bounds__(256) void gemm_kv(
    const bf16* __restrict__ A, int lda,
    const bf16* __restrict__ Bt, int ldb,
    bf16* __restrict__ kbuf, bf16* __restrict__ vT, int K) {
    __shared__ bf16 As[128 * 32];
    __shared__ bf16 Bs[128 * 32];
    const int m0 = blockIdx.y * 128;
    const int n0 = blockIdx.x * 128;
    const int tid = threadIdx.x;
    const int lane = tid & 63;
    const int wave = tid >> 6;
    const int wm = (wave >> 1) * 64;
    const int wn = (wave & 1) * 64;
    const int lr = lane & 15;
    const int lq = lane >> 4;
    const int sr = tid >> 2;
    const int sc = (tid & 3) * 8;
    const int wbase = wave * 512;

    f32x4 acc[4][4] = {};

    for (int k0 = 0; k0 < K; k0 += 32) {
        __syncthreads();
        async_cp16(A + (size_t)(m0 + sr) * lda + k0 + sc, As + wbase);
        async_cp16(A + (size_t)(m0 + sr + 64) * lda + k0 + sc, As + 2048 + wbase);
        async_cp16(Bt + (size_t)(n0 + sr) * ldb + k0 + sc, Bs + wbase);
        async_cp16(Bt + (size_t)(n0 + sr + 64) * ldb + k0 + sc, Bs + 2048 + wbase);
        __syncthreads();
        bf16x8 af[4], bfr[4];
        #pragma unroll
        for (int t = 0; t < 4; ++t) {
            af[t]  = *(const bf16x8*)(As + (wm + t * 16 + lr) * 32 + lq * 8);
            bfr[t] = *(const bf16x8*)(Bs + (wn + t * 16 + lr) * 32 + lq * 8);
        }
        #pragma unroll
        for (int mt = 0; mt < 4; ++mt)
            #pragma unroll
            for (int nt = 0; nt < 4; ++nt)
                acc[mt][nt] = MFMA16(af[mt], bfr[nt], acc[mt][nt]);
    }
    #pragma unroll
    for (int mt = 0; mt < 4; ++mt)
        #pragma unroll
        for (int nt = 0; nt < 4; ++nt) {
            int colbase = n0 + wn + nt * 16;
            int h = colbase >> 8;
            int rr = (colbase & 255) + lr;
            #pragma unroll
            for (int r = 0; r < 4; ++r) {
                int row = m0 + wm + mt * 16 + lq * 4 + r;
                bf16 val = __float2bfloat16(acc[mt][nt][r]);
                if (rr < 128) {
                    kbuf[(size_t)row * 2048 + h * 128 + rr] = val;
                } else {
                    int dv = rr - 128;
                    int b = row >> 11, s = row & 2047;
                    vT[((size_t)((b * 16 + h) * 128 + dv)) * 2048 + s] = val;
                }
            }
        }
}

// ---------------------------------------------------------------------------
__global__ void rope_kernel(bf16* __restrict__ XW) {
    int v = blockIdx.x;
    int row = blockIdx.y * 4 + threadIdx.y;
    int i = threadIdx.x;
    int s = row & 2047;
    int cbase = (v < 16) ? v * 192 + 128 : 3072;
    size_t base = (size_t)row * 3712 + cbase;
    float xi = __bfloat162float(XW[base + i]);
    float xp = __shfl_xor(xi, 32);
    int j = i & 31;
    float inv = exp2f(-(float)j * (13.287712379549449f / 32.0f));
    float ang = (float)s * inv;
    float c = cosf(ang), sn = sinf(ang);
    float res = (i < 32) ? (xi * c - xp * sn) : (xi * c + xp * sn);
    XW[base + i] = __float2bfloat16(res);
}

// ---------------------------------------------------------------------------
// Flash attention pass 1 (causal), split-K, S^T orientation.
// grid (24, 32 bh), block 256 (4 waves x 32 q rows).
// S^T = K·Q^T via MFMA(A=K-frag, B=Q-frag): C col = q (lane&15), row = key
// (lq*4+r). Key-reduction: in-register over r/mt + 2 shuffles over lq.
// O accumulated as O^T (A=V^T-frag, B=P-frag), transposed via LDS epilogue.
// m/l tracked in log2 domain.
// ---------------------------------------------------------------------------
__global__ __launch_bounds__(256) void attn_kernel(
    const bf16* __restrict__ XW, const bf16* __restrict__ kbuf,
    const bf16* __restrict__ vT, bf16* __restrict__ attn_out,
    bf16* __restrict__ opart, float* __restrict__ mlbuf) {
    const int bh = blockIdx.y, b = bh >> 4, h = bh & 15;
    const int bx = blockIdx.x;
    int qt, ck, ks, ke;
    bool partial;
    if (bx < 8)       { qt = bx;     ck = 0; partial = false; ks = 0;    ke = (qt + 1) * 128; }
    else if (bx < 16) { qt = bx;     ck = 0; partial = true;  ks = 0;    ke = 1024; }
    else              { qt = bx - 8; ck = 1; partial = true;  ks = 1024; ke = (qt + 1) * 128; }

    const int tid = threadIdx.x;
    const int wave = tid >> 6;
    const int lane = tid & 63;
    const int lr = lane & 15, lq = lane >> 4;
    const int qw = qt * 128 + wave * 32;

    __shared__ bf16 Ks[64 * 200];
    __shared__ bf16 Vs[128 * 72];
    __shared__ bf16 Pm[4 * 32 * 72];   // per-wave 32x72; reused as 16x136 Tr in epilogue
    bf16* Pw = Pm + wave * (32 * 72);

    const bf16* xwb = XW + (size_t)b * 2048 * 3712;
    const bf16* kb  = kbuf + (size_t)b * 2048 * 2048;
    const bf16* vTb = vT + (size_t)bh * 128 * 2048;

    // Q B-frags: [n=q(lane&15)][k=lq*8..], 2 nf groups x 6 feature chunks
    bf16x8 qf[2][6];
    #pragma unroll
    for (int nf = 0; nf < 2; ++nf) {
        size_t ro = (size_t)(qw + nf * 16 + lr) * 3712 + h * 192;
        #pragma unroll
        for (int c = 0; c < 6; ++c)
            qf[nf][c] = *(const bf16x8*)(xwb + ro + c * 32 + lq * 8);
    }

    f32x4 o[2][8] = {};      // O^T: [nf][dt], col=q, row=dv
    float m_i[2], l_i[2];
    m_i[0] = m_i[1] = -1e30f;
    l_i[0] = l_i[1] = 0.0f;

    const float sc2 = 0.07216878364870323f * 1.4426950408889634f;  // scale*log2(e)

    const int krow = tid >> 2, kcg = tid & 3;
    const int vrow = tid >> 1, vcg = tid & 1;

    uint4 kn[4], krp[2], vv[4];
    #define PREFETCH(NP) do {                                                     \
        const bf16* kr_ = kb + (size_t)((NP) + krow) * 2048 + h * 128 + kcg * 32; \
        kn[0] = *(const uint4*)(kr_);      kn[1] = *(const uint4*)(kr_ + 8);      \
        kn[2] = *(const uint4*)(kr_ + 16); kn[3] = *(const uint4*)(kr_ + 24);     \
        const bf16* xr_ = xwb + (size_t)((NP) + krow) * 3712 + 3072 + kcg * 16;   \
        krp[0] = *(const uint4*)(xr_);     krp[1] = *(const uint4*)(xr_ + 8);     \
        const bf16* vr_ = vTb + (size_t)vrow * 2048 + (NP) + vcg * 32;            \
        vv[0] = *(const uint4*)(vr_);      vv[1] = *(const uint4*)(vr_ + 8);      \
        vv[2] = *(const uint4*)(vr_ + 16); vv[3] = *(const uint4*)(vr_ + 24);     \
    } while (0)

    PREFETCH(ks);

    for (int n0 = ks; n0 < ke; n0 += 64) {
        __syncthreads();
        #pragma unroll
        for (int i = 0; i < 4; ++i)
            *(uint4*)(Ks + krow * 200 + kcg * 32 + i * 8) = kn[i];
        *(uint4*)(Ks + krow * 200 + 128 + kcg * 16) = krp[0];
        *(uint4*)(Ks + krow * 200 + 128 + kcg * 16 + 8) = krp[1];
        #pragma unroll
        for (int i = 0; i < 4; ++i)
            *(uint4*)(Vs + vrow * 72 + vcg * 32 + i * 8) = vv[i];
        __syncthreads();
        if (n0 + 64 < ke) PREFETCH(n0 + 64);   // overlap next tile's loads with compute

        if (n0 < qw + 32) {  // wave-uniform: skip fully-masked tiles
            // ---- S^T = K Q^T: 24 LDS reads, 48 MFMAs ----
            f32x4 st[4][2] = {};   // [mt(key)][nf(q)]
            #pragma unroll
            for (int c = 0; c < 6; ++c) {
                #pragma unroll
                for (int mt = 0; mt < 4; ++mt) {
                    bf16x8 kf = *(const bf16x8*)(Ks + (mt * 16 + lr) * 200 + c * 32 + lq * 8);
                    st[mt][0] = MFMA16(kf, qf[0][c], st[mt][0]);
                    st[mt][1] = MFMA16(kf, qf[1][c], st[mt][1]);
                }
            }
            // ---- vectorized online softmax (per nf: 1 q per lane, 16 keys) ----
            #pragma unroll
            for (int nf = 0; nf < 2; ++nf) {
                int q = qw + nf * 16 + lr;
                f32x4 a[4];
                #pragma unroll
                for (int mt = 0; mt < 4; ++mt)
                    #pragma unroll
                    for (int r = 0; r < 4; ++r) {
                        int kid = n0 + mt * 16 + lq * 4 + r;
                        a[mt][r] = (kid <= q) ? st[mt][nf][r] * sc2 : -1e30f;
                    }
                f32x4 m4 = a[0];
                #pragma unroll
                for (int mt = 1; mt < 4; ++mt)
                    #pragma unroll
                    for (int r = 0; r < 4; ++r) m4[r] = fmaxf(m4[r], a[mt][r]);
                float vm = fmaxf(fmaxf(m4[0], m4[1]), fmaxf(m4[2], m4[3]));
                vm = fmaxf(vm, __shfl_xor(vm, 16));
                vm = fmaxf(vm, __shfl_xor(vm, 32));
                float mnew = fmaxf(m_i[nf], vm);
                float alpha = exp2f(m_i[nf] - mnew);
                m_i[nf] = mnew;
                float ps = 0.0f;
                #pragma unroll
                for (int mt = 0; mt < 4; ++mt) {
                    unsigned short pk[4];
                    #pragma unroll
                    for (int r = 0; r < 4; ++r) {
                        float p = exp2f(a[mt][r] - mnew);
                        ps += p;
                        pk[r] = f2bu(p);
                    }
                    *(uint2*)((unsigned short*)Pw + (nf * 16 + lr) * 72 + mt * 16 + lq * 4) =
                        *(uint2*)pk;
                }
                ps += __shfl_xor(ps, 16);
                ps += __shfl_xor(ps, 32);
                l_i[nf] = l_i[nf] * alpha + ps;
                #pragma unroll
                for (int dt = 0; dt < 8; ++dt)
                    #pragma unroll
                    for (int r = 0; r < 4; ++r) o[nf][dt][r] *= alpha;
            }
            // in-wave LDS RAW
            __asm__ volatile("s_waitcnt lgkmcnt(0)" ::: "memory");
            bf16x8 ptf[2][2];
            #pragma unroll
            for (int nf = 0; nf < 2; ++nf)
                #pragma unroll
                for (int kt = 0; kt < 2; ++kt)
                    ptf[nf][kt] = *(const bf16x8*)(Pw + (nf * 16 + lr) * 72 + kt * 32 + lq * 8);
            // ---- O^T += V^T P: 16 LDS reads, 32 MFMAs ----
            #pragma unroll
            for (int kt = 0; kt < 2; ++kt)
                #pragma unroll
                for (int dt = 0; dt < 8; ++dt) {
                    bf16x8 vf = *(const bf16x8*)(Vs + (dt * 16 + lr) * 72 + kt * 32 + lq * 8);
                    o[0][dt] = MFMA16(vf, ptf[0][kt], o[0][dt]);
                    o[1][dt] = MFMA16(vf, ptf[1][kt], o[1][dt]);
                }
        }
    }
    #undef PREFETCH

    // ---- epilogue: transpose O^T -> O via per-wave LDS, coalesced stores ----
    #pragma unroll
    for (int nf = 0; nf < 2; ++nf) {
        float wsc = partial ? 1.0f : (1.0f / l_i[nf]);
        __asm__ volatile("s_waitcnt lgkmcnt(0)" ::: "memory");
        #pragma unroll
        for (int dt = 0; dt < 8; ++dt) {
            unsigned short pk[4];
            #pragma unroll
            for (int r = 0; r < 4; ++r) pk[r] = f2bu(o[nf][dt][r] * wsc);
            *(uint2*)((unsigned short*)Pw + lr * 136 + dt * 16 + lq * 4) = *(uint2*)pk;
        }
        __asm__ volatile("s_waitcnt lgkmcnt(0)" ::: "memory");
        int ql = lane >> 2, cs = (lane & 3) * 32;
        int qrow = qw + nf * 16 + ql;
        uint4 d[4];
        #pragma unroll
        for (int k = 0; k < 4; ++k)
            d[k] = *(const uint4*)(Pw + ql * 136 + cs + k * 8);
        bf16* dst;
        if (!partial) {
            dst = attn_out + (size_t)(b * 2048 + qrow) * 2048 + h * 128 + cs;
        } else {
            dst = opart + ((size_t)((b * 1024 + (qrow - 1024)) * 2 + ck)) * 2048 + h * 128 + cs;
        }
        #pragma unroll
        for (int k = 0; k < 4; ++k) *(uint4*)(dst + k * 8) = d[k];
        if (partial && lane < 16) {
            int q2 = qw + nf * 16 + lane;
            float* mlp = mlbuf + (((size_t)(b * 1024 + (q2 - 1024)) * 2 + ck) * 16 + h) * 2;
            mlp[0] = m_i[nf];   // log2 domain
            mlp[1] = l_i[nf];
        }
    }
}

// ---------------------------------------------------------------------------
// Merge the two key-chunks for q rows >= 1024. m values are in log2 domain.
// ---------------------------------------------------------------------------
__global__ void attn_merge(const bf16* __restrict__ opart,
                           const float* __restrict__ mlbuf,
                           bf16* __restrict__ attn_out) {
    int bu = blockIdx.x;            // b*1024 + urow
    int b = bu >> 10, urow = bu & 1023;
    int h = blockIdx.y * 2 + threadIdx.y;
    int tx = threadIdx.x;
    const float* mlp = mlbuf + (((size_t)bu * 2) * 16 + h) * 2;
    float m0 = mlp[0], l0 = mlp[1];
    float m1 = mlp[32], l1 = mlp[33];
    size_t ob = ((size_t)bu * 2) * 2048 + h * 128 + tx;
    float o0 = __bfloat162float(opart[ob]);
    float o1 = __bfloat162float(opart[ob + 2048]);
    float m = fmaxf(m0, m1);
    float w0 = exp2f(m0 - m);
    float w1 = exp2f(m1 - m);
    float v = (o0 * w0 + o1 * w1) / (l0 * w0 + l1 * w1);
    attn_out[((size_t)(b * 2048 + 1024 + urow)) * 2048 + h * 128 + tx] = __float2bfloat16(v);
}

// ---------------------------------------------------------------------------
extern "C" void kernel_launch(void* const* d_in, const int* in_sizes, int n_in,
                              void* d_out, int out_size, void* d_ws, size_t ws_size,
                              hipStream_t stream) {
    const float* x    = (const float*)d_in[0];
    const float* Wq   = (const float*)d_in[1];
    const float* Wdkv = (const float*)d_in[2];
    const float* Wkr  = (const float*)d_in[3];
    const float* Wukv = (const float*)d_in[4];
    const float* Wo   = (const float*)d_in[5];
    float* out = (float*)d_out;

    // Workspace layout (98,041,856 bytes), time-sliced aliasing (see r1-r5).
    char* ws = (char*)d_ws;
    bf16* XW       = (bf16*)(ws);
    bf16* kbuf     = (bf16*)(ws + 30408704);
    bf16* vT       = (bf16*)(ws + 47185920);
    bf16* attn_out = (bf16*)(ws + 63963136);
    bf16* opart    = (bf16*)(ws + 80740352);
    float* mlbuf   = (float*)(ws + 97517568);
    bf16* xb       = (bf16*)(ws + 30408704);  // alias kbuf
    bf16* WcatT    = (bf16*)(ws + 47185920);  // alias vT
    bf16* WukvT    = (bf16*)(ws + 63963136);  // alias attn_out
    bf16* WoT      = (bf16*)(ws + 47185920);  // alias vT (after attn)

    dim3 tb(32, 8);
    cvt_fp32_bf16<<<8192, 256, 0, stream>>>(x, xb);
    wtrans<<<dim3(96, 64), tb, 0, stream>>>(Wq, WcatT, 2048, 3072);
    wtrans<<<dim3(2, 64), tb, 0, stream>>>(Wkr, WcatT + (size_t)3072 * 2048, 2048, 64);
    wtrans<<<dim3(16, 64), tb, 0, stream>>>(Wdkv, WcatT + (size_t)3136 * 2048, 2048, 512);
    zerofill<<<512, 256, 0, stream>>>(WcatT + (size_t)3648 * 2048);
    wtrans<<<dim3(128, 16), tb, 0, stream>>>(Wukv, WukvT, 512, 4096);

    gemm_bt<bf16><<<dim3(29, 32), 256, 0, stream>>>(xb, 2048, WcatT, 2048, XW, 3712, 2048);
    rope_kernel<<<dim3(17, 1024), dim3(64, 4), 0, stream>>>(XW);
    gemm_kv<<<dim3(32, 32), 256, 0, stream>>>(XW + 3136, 3712, WukvT, 512, kbuf, vT, 512);
    attn_kernel<<<dim3(24, 32), 256, 0, stream>>>(XW, kbuf, vT, attn_out, opart, mlbuf);
    attn_merge<<<dim3(2048, 8), dim3(128, 2), 0, stream>>>(opart, mlbuf, attn_out);
    wtrans<<<dim3(64, 64), tb, 0, stream>>>(Wo, WoT, 2048, 2048);
    gemm_bt<float><<<dim3(16, 32), 256, 0, stream>>>(attn_out, 2048, WoT, 2048, out, 2048, 2048);
}